// Round 2
// baseline (249.192 us; speedup 1.0000x reference)
//
#include <hip/hip_runtime.h>

// out = (I + W + ... + W^10) x == M . x  (M 256x256, exactly banded +-70).
// K1: build M per column, split-precision bf16 Mh/Ml (row-major).
// K2: banded MFMA GEMM, latency-decoupled:
//     - double-buffered LDS (H/L interleaved): ONE raw barrier per tile
//       (s_waitcnt lgkmcnt(0) + s_barrier) -> NO vmcnt drain: next-tile
//       register prefetch and output stores stay in flight across barriers
//     - A fragments refetched from L2 each tile with a manual 2-deep
//       software pipeline (load chunk i+1 under MFMA of chunk i)
//     - ds_read_b64 B-fragments (H,L adjacent), 2-way bank alias = free

#define NCH 256
#define PAD 7
#define SCOPE 15
#define SPATIAL 3136
#define PER_B 802816          // 256*3136
#define STW 32                // spatial tile width
#define STILES_PER_B 98       // 3136/32
#define NTILES 3136           // 32*98
#define GRID_APPLY 512
#define MAXCH 12              // max K-chunks (of 16) per wave band window
#define BUFW 8192             // words per LDS buffer: 128 k2-rows * 32 * 2

typedef __attribute__((ext_vector_type(8))) __bf16 bf16x8;
typedef __attribute__((ext_vector_type(16))) float float16;
typedef __attribute__((ext_vector_type(4))) unsigned int uint4v;
typedef __attribute__((ext_vector_type(2))) unsigned int uint2v;

static __device__ __forceinline__ unsigned short f2bf_rn_u(float f) {
  unsigned u = __builtin_bit_cast(unsigned int, f);
  return (unsigned short)((u + 0x7FFFu + ((u >> 16) & 1u)) >> 16);
}
static __device__ __forceinline__ float bf2f_u(unsigned short h) {
  unsigned u = ((unsigned)h) << 16;
  return __builtin_bit_cast(float, u);
}
static __device__ __forceinline__ unsigned pack_bf2(float a, float b) {
  return (unsigned)f2bf_rn_u(a) | ((unsigned)f2bf_rn_u(b) << 16);
}
// split floats (a,b) -> hi packed word + lo (residual) packed word
static __device__ __forceinline__ void split2(float a, float b,
                                              unsigned& h, unsigned& l) {
  h = pack_bf2(a, b);
  const float ra = a - __builtin_bit_cast(float, h << 16);
  const float rb = b - __builtin_bit_cast(float, h & 0xFFFF0000u);
  l = pack_bf2(ra, rb);
}

// ---- Kernel 1: build M column d (block d), write bf16 hi/lo row-major ----
__global__ void build_M_kernel(const float* __restrict__ w,
                               const int* __restrict__ max_steps_p,
                               unsigned short* __restrict__ Mh,
                               unsigned short* __restrict__ Ml) {
  const int d = blockIdx.x;
  const int c = threadIdx.x;
  __shared__ float v[2][NCH];
  __shared__ float wsh[SCOPE];
  if (c < SCOPE) wsh[c] = w[c];
  const float e = (c == d) ? 1.0f : 0.0f;
  v[0][c] = e;
  __syncthreads();
  const int steps = *max_steps_p;
  int cur = 0;
  for (int t = 0; t < steps; ++t) {
    float s = e;
#pragma unroll
    for (int j = 0; j < SCOPE; ++j) {
      const int cc = c + j - PAD;
      if (cc >= 0 && cc < NCH) s += wsh[j] * v[cur][cc];
    }
    cur ^= 1;
    v[cur][c] = s;
    __syncthreads();
  }
  const float f = v[cur][c];
  const unsigned short h = f2bf_rn_u(f);
  Mh[c * NCH + d] = h;
  Ml[c * NCH + d] = f2bf_rn_u(f - bf2f_u(h));
}

// ---- Kernel 2 -------------------------------------------------------------
// 512 threads (8 waves); wave w -> output channels [32w,32w+32).
// LDS layout XB: [buf][k2 0..127][n 0..31][H,L] packed bf16-pair words,
// H word (k2,n) = (bf16(x[2k2][n]), bf16(x[2k2+1][n])), L = residual.
__global__ __launch_bounds__(512, 4) void apply_M_kernel(
    const float* __restrict__ x, const unsigned short* __restrict__ Mh,
    const unsigned short* __restrict__ Ml, float* __restrict__ out) {
  __shared__ unsigned XB[2 * BUFW];  // 64 KB

  const int tid  = threadIdx.x;
  const int lane = tid & 63;
  const int w    = tid >> 6;
  const int m    = lane & 31;  // A row in c-tile == B spatial col
  const int half = lane >> 5;  // k-half
  const int c0   = w * 32;

  // exact nonzero band: rows [c0, c0+31] touch cols [c0-70, c0+101]
  int clo = c0 - 70; if (clo < 0) clo = 0; clo >>= 4;
  int chi = c0 + 101; if (chi > 255) chi = 255; chi >>= 4;
  const int nch = chi - clo + 1;  // 7..12 per wave

  // per-thread A base (row-major); chunk i lives at +i*16 shorts.
  // NOT kept live across tiles: refetched from L2 each tile (M stays L2-hot).
  const unsigned short* mh = Mh + (c0 + m) * NCH + clo * 16 + half * 8;
  const unsigned short* ml = Ml + (c0 + m) * NCH + clo * 16 + half * 8;

  // loader geometry: thread -> (d-pair rows dg, dg+64; 4 spatial cols sq..sq+3)
  const int sq = (tid & 7) * 4;
  const int dg = tid >> 3;  // 0..63

  int tau = blockIdx.x;
  int bo = 0;  // double-buffer word offset (0 / BUFW)
  float4 g0, g1, g2, g3;
  {
    const float* gb = x + (size_t)(tau / STILES_PER_B) * PER_B
                        + (size_t)(tau % STILES_PER_B) * STW;
    g0 = *(const float4*)(gb + (size_t)(2 * dg) * SPATIAL + sq);
    g1 = *(const float4*)(gb + (size_t)(2 * dg + 1) * SPATIAL + sq);
    g2 = *(const float4*)(gb + (size_t)(2 * dg + 128) * SPATIAL + sq);
    g3 = *(const float4*)(gb + (size_t)(2 * dg + 129) * SPATIAL + sq);
  }

#pragma unroll 1
  for (; tau < NTILES; tau += GRID_APPLY) {
    // cooperative split: registers -> interleaved (H,L) words in LDS buf bo.
    // Writing the OTHER buffer than last tile's readers -> no front barrier.
    {
      unsigned h0, h1, h2, h3, l0, l1, l2, l3;
      split2(g0.x, g1.x, h0, l0); split2(g0.y, g1.y, h1, l1);
      split2(g0.z, g1.z, h2, l2); split2(g0.w, g1.w, h3, l3);
      unsigned* p = &XB[bo + dg * 64 + sq * 2];
      *(uint4v*)(p)     = (uint4v){h0, l0, h1, l1};
      *(uint4v*)(p + 4) = (uint4v){h2, l2, h3, l3};
      split2(g2.x, g3.x, h0, l0); split2(g2.y, g3.y, h1, l1);
      split2(g2.z, g3.z, h2, l2); split2(g2.w, g3.w, h3, l3);
      unsigned* q = &XB[bo + (dg + 64) * 64 + sq * 2];
      *(uint4v*)(q)     = (uint4v){h0, l0, h1, l1};
      *(uint4v*)(q + 4) = (uint4v){h2, l2, h3, l3};
    }

    // prefetch next tile into registers BEFORE the barrier; raw s_barrier
    // does not drain vmcnt, so these stay in flight across compute
    const int ntau = tau + GRID_APPLY;
    if (ntau < NTILES) {
      const float* gb = x + (size_t)(ntau / STILES_PER_B) * PER_B
                          + (size_t)(ntau % STILES_PER_B) * STW;
      g0 = *(const float4*)(gb + (size_t)(2 * dg) * SPATIAL + sq);
      g1 = *(const float4*)(gb + (size_t)(2 * dg + 1) * SPATIAL + sq);
      g2 = *(const float4*)(gb + (size_t)(2 * dg + 128) * SPATIAL + sq);
      g3 = *(const float4*)(gb + (size_t)(2 * dg + 129) * SPATIAL + sq);
    }

    // LDS writes visible to all waves; loads/stores NOT drained
    asm volatile("s_waitcnt lgkmcnt(0)" ::: "memory");
    __builtin_amdgcn_s_barrier();

    // opaque copies: compiler cannot hoist the A loads out of the tau loop
    const unsigned short* mhp = mh;
    const unsigned short* mlp = ml;
    asm volatile("" : "+v"(mhp), "+v"(mlp));

    // two accumulator chains: main (hi*hi) and merged correction (hi*lo+lo*hi)
    float16 a0, a1;
#pragma unroll
    for (int q = 0; q < 16; ++q) { a0[q] = 0.0f; a1[q] = 0.0f; }

    // manual 2-deep pipeline: A-chunk i+1 loads fly under chunk i's MFMAs
    bf16x8 cAh = *(const bf16x8*)(mhp);
    bf16x8 cAl = *(const bf16x8*)(mlp);
#pragma unroll
    for (int i = 0; i < MAXCH; ++i) {
      if (i < nch) {
        bf16x8 nAh, nAl;
        if (i + 1 < nch) {
          nAh = *(const bf16x8*)(mhp + (i + 1) * 16);
          nAl = *(const bf16x8*)(mlp + (i + 1) * 16);
        }
        const int k2b = (clo + i) * 8 + half * 4;
        const unsigned* bp = &XB[bo + k2b * 64 + 2 * m];
        const uint2v r0 = *(const uint2v*)(bp);
        const uint2v r1 = *(const uint2v*)(bp + 64);
        const uint2v r2 = *(const uint2v*)(bp + 128);
        const uint2v r3 = *(const uint2v*)(bp + 192);
        const uint4v hw = {r0.x, r1.x, r2.x, r3.x};
        const uint4v lw = {r0.y, r1.y, r2.y, r3.y};
        const bf16x8 bh = __builtin_bit_cast(bf16x8, hw);
        const bf16x8 bl = __builtin_bit_cast(bf16x8, lw);
        a0 = __builtin_amdgcn_mfma_f32_32x32x16_bf16(cAh, bh, a0, 0, 0, 0);
        a1 = __builtin_amdgcn_mfma_f32_32x32x16_bf16(cAh, bl, a1, 0, 0, 0);
        a1 = __builtin_amdgcn_mfma_f32_32x32x16_bf16(cAl, bh, a1, 0, 0, 0);
        cAh = nAh; cAl = nAl;
      }
    }

    // epilogue: C/D map (32x32): col = lane&31, row = (r&3)+8*(r>>2)+4*half
    // stores are fire-and-forget; nothing ever drains them mid-kernel
    const int b  = tau / STILES_PER_B;
    const int s0 = (tau % STILES_PER_B) * STW;
    float* ob = out + (size_t)b * PER_B + (size_t)s0 + m;
#pragma unroll
    for (int r = 0; r < 16; ++r) {
      const int row = (r & 3) + 8 * (r >> 2) + 4 * half;
      ob[(size_t)(c0 + row) * SPATIAL] = a0[r] + a1[r];
    }

    bo ^= BUFW;
  }
}

extern "C" void kernel_launch(void* const* d_in, const int* in_sizes, int n_in,
                              void* d_out, int out_size, void* d_ws, size_t ws_size,
                              hipStream_t stream) {
  const float* x = (const float*)d_in[0];  // (32, 256, 56, 56) fp32
  const float* w = (const float*)d_in[1];  // (15,) fp32
  const int* ms = (const int*)d_in[2];     // scalar int (10)
  float* out = (float*)d_out;              // (32, 256, 56, 56) fp32

  unsigned short* Mh = (unsigned short*)d_ws;  // 128 KB
  unsigned short* Ml = Mh + NCH * NCH;         // 128 KB

  build_M_kernel<<<NCH, NCH, 0, stream>>>(w, ms, Mh, Ml);
  apply_M_kernel<<<GRID_APPLY, 512, 0, stream>>>(x, Mh, Ml, out);
}

// Round 5
// 208.416 us; speedup vs baseline: 1.1956x; 1.1956x over previous
//
#include <hip/hip_runtime.h>

// out = (I + W + ... + W^10) x == M . x  (M 256x256, exactly banded +-70).
// K1: build M per column; write split-precision bf16 hi/lo DIRECTLY in
//     per-(wave,chunk,lane) MFMA A-fragment layout (no row-major copy, no
//     relayout pass -> workspace stays 192 KB, inside the proven envelope;
//     R3/R4's 448 KB workspace is the prime suspect for the container
//     faults: possible OOB writes past ws_size).
// K2: one 32-spatial tile per block (grid 3136), NO in-kernel loop:
//     hardware block streaming provides cross-tile pipelining (R0-R2 showed
//     the in-kernel persistent loop is a single latency chain at ~40k
//     cycles/tile regardless of structure; TLP is the only thing that
//     scaled). 4 blocks/CU: 32KB LDS, __launch_bounds__(512,8) (VGPR<=64).

#define NCH 256
#define PAD 7
#define SCOPE 15
#define SPATIAL 3136
#define PER_B 802816          // 256*3136
#define STW 32                // spatial tile width
#define STILES_PER_B 98       // 3136/32
#define NTILES 3136           // 32*98 = one block per tile
#define MAXCH 12              // max K-chunks (of 16) per wave band window

typedef __attribute__((ext_vector_type(8))) __bf16 bf16x8;
typedef __attribute__((ext_vector_type(16))) float float16;
typedef __attribute__((ext_vector_type(4))) unsigned int uint4v;
typedef __attribute__((ext_vector_type(2))) unsigned int uint2v;

static __device__ __forceinline__ unsigned short f2bf_rn_u(float f) {
  unsigned u = __builtin_bit_cast(unsigned int, f);
  return (unsigned short)((u + 0x7FFFu + ((u >> 16) & 1u)) >> 16);
}
static __device__ __forceinline__ float bf2f_u(unsigned short h) {
  unsigned u = ((unsigned)h) << 16;
  return __builtin_bit_cast(float, u);
}
static __device__ __forceinline__ unsigned pack_bf2(float a, float b) {
  return (unsigned)f2bf_rn_u(a) | ((unsigned)f2bf_rn_u(b) << 16);
}
// split floats (a,b) -> hi packed word + lo (residual) packed word
static __device__ __forceinline__ void split2(float a, float b,
                                              unsigned& h, unsigned& l) {
  h = pack_bf2(a, b);
  const float ra = a - __builtin_bit_cast(float, h << 16);
  const float rb = b - __builtin_bit_cast(float, h & 0xFFFF0000u);
  l = pack_bf2(ra, rb);
}

// ---- Kernel 1: build M column d (block d); store fragment-layout hi/lo ----
// Fragment slot (w, i, lane) short j holds M[32w + (lane&31)]
// [(clo(w)+i)*16 + (lane>>5)*8 + j]; thread (d,c) owns element (c,d) and
// writes it to its unique slot. Slots with i >= nch(w) are never read.
__global__ void build_M_kernel(const float* __restrict__ w,
                               const int* __restrict__ max_steps_p,
                               unsigned short* __restrict__ AhF,
                               unsigned short* __restrict__ AlF) {
  const int d = blockIdx.x;
  const int c = threadIdx.x;
  __shared__ float v[2][NCH];
  __shared__ float wsh[SCOPE];
  if (c < SCOPE) wsh[c] = w[c];
  const float e = (c == d) ? 1.0f : 0.0f;
  v[0][c] = e;
  __syncthreads();
  const int steps = *max_steps_p;
  int cur = 0;
  for (int t = 0; t < steps; ++t) {
    float s = e;
#pragma unroll
    for (int j = 0; j < SCOPE; ++j) {
      const int cc = c + j - PAD;
      if (cc >= 0 && cc < NCH) s += wsh[j] * v[cur][cc];
    }
    cur ^= 1;
    v[cur][c] = s;
    __syncthreads();
  }
  const float f = v[cur][c];
  const unsigned short h = f2bf_rn_u(f);
  const unsigned short l = f2bf_rn_u(f - bf2f_u(h));

  const int wv = c >> 5;
  const int c0 = wv * 32;
  int clo = c0 - 70; if (clo < 0) clo = 0; clo >>= 4;
  int chi = c0 + 101; if (chi > 255) chi = 255; chi >>= 4;
  const int ch = d >> 4;
  if (ch >= clo && ch <= chi) {
    const int i    = ch - clo;
    const int half = (d >> 3) & 1;
    const int j    = d & 7;
    const int lane = half * 32 + (c & 31);
    const size_t dst = ((size_t)(wv * MAXCH + i) * 64 + lane) * 8 + j;
    AhF[dst] = h;
    AlF[dst] = l;
  }
}

// ---- Kernel 2 -------------------------------------------------------------
// 512 threads (8 waves); wave w -> output channels [32w,32w+32) of ONE tile.
// LDS XB: [k2 0..127][n 0..31][H,L] packed bf16-pair words,
// H word (k2,n) = (bf16(x[2k2][n]), bf16(x[2k2+1][n])), L = residual.
__global__ __launch_bounds__(512, 8) void apply_M_kernel(
    const float* __restrict__ x, const unsigned short* __restrict__ AhF,
    const unsigned short* __restrict__ AlF, float* __restrict__ out) {
  __shared__ unsigned XB[8192];  // 32 KB

  const int tid  = threadIdx.x;
  const int lane = tid & 63;
  const int w    = tid >> 6;
  const int m    = lane & 31;  // A row in c-tile == B spatial col
  const int half = lane >> 5;  // k-half
  const int c0   = w * 32;

  // exact nonzero band: rows [c0, c0+31] touch cols [c0-70, c0+101]
  int clo = c0 - 70; if (clo < 0) clo = 0; clo >>= 4;
  int chi = c0 + 101; if (chi > 255) chi = 255; chi >>= 4;
  const int nch = chi - clo + 1;  // 7..12 per wave

  // loader geometry: thread -> (d-pair rows dg, dg+64; 4 spatial cols sq..sq+3)
  const int sq = (tid & 7) * 4;
  const int dg = tid >> 3;  // 0..63

  const int tau = blockIdx.x;
  const float* gb = x + (size_t)(tau / STILES_PER_B) * PER_B
                      + (size_t)(tau % STILES_PER_B) * STW;
  const float4 g0 = *(const float4*)(gb + (size_t)(2 * dg) * SPATIAL + sq);
  const float4 g1 = *(const float4*)(gb + (size_t)(2 * dg + 1) * SPATIAL + sq);
  const float4 g2 = *(const float4*)(gb + (size_t)(2 * dg + 128) * SPATIAL + sq);
  const float4 g3 = *(const float4*)(gb + (size_t)(2 * dg + 129) * SPATIAL + sq);

  // cooperative split: registers -> interleaved (H,L) words in LDS
  {
    unsigned h0, h1, h2, h3, l0, l1, l2, l3;
    split2(g0.x, g1.x, h0, l0); split2(g0.y, g1.y, h1, l1);
    split2(g0.z, g1.z, h2, l2); split2(g0.w, g1.w, h3, l3);
    unsigned* p = &XB[dg * 64 + sq * 2];
    *(uint4v*)(p)     = (uint4v){h0, l0, h1, l1};
    *(uint4v*)(p + 4) = (uint4v){h2, l2, h3, l3};
    split2(g2.x, g3.x, h0, l0); split2(g2.y, g3.y, h1, l1);
    split2(g2.z, g3.z, h2, l2); split2(g2.w, g3.w, h3, l3);
    unsigned* q = &XB[(dg + 64) * 64 + sq * 2];
    *(uint4v*)(q)     = (uint4v){h0, l0, h1, l1};
    *(uint4v*)(q + 4) = (uint4v){h2, l2, h3, l3};
  }
  __syncthreads();

  // A-fragment base for this (wave, lane); chunk i at +i*512 shorts.
  // Coalesced (lane-consecutive 16B), L2-hot (shared by all 3136 blocks).
  const unsigned short* mhp = AhF + ((size_t)(w * MAXCH) * 64 + lane) * 8;
  const unsigned short* mlp = AlF + ((size_t)(w * MAXCH) * 64 + lane) * 8;
  // opaque: keep compiler from hoisting/batching all 24 frag loads (VGPR cap)
  asm volatile("" : "+v"(mhp), "+v"(mlp));

  // two accumulator chains: main (hi*hi) and merged correction (hi*lo+lo*hi)
  float16 a0, a1;
#pragma unroll
  for (int q = 0; q < 16; ++q) { a0[q] = 0.0f; a1[q] = 0.0f; }

#pragma unroll
  for (int i = 0; i < MAXCH; ++i) {
    if (i < nch) {
      const bf16x8 Ah = *(const bf16x8*)(mhp + i * 512);
      const bf16x8 Al = *(const bf16x8*)(mlp + i * 512);
      const int k2b = (clo + i) * 8 + half * 4;
      const unsigned* bp = &XB[k2b * 64 + 2 * m];
      const uint2v r0 = *(const uint2v*)(bp);
      const uint2v r1 = *(const uint2v*)(bp + 64);
      const uint2v r2 = *(const uint2v*)(bp + 128);
      const uint2v r3 = *(const uint2v*)(bp + 192);
      const uint4v hw = {r0.x, r1.x, r2.x, r3.x};
      const uint4v lw = {r0.y, r1.y, r2.y, r3.y};
      const bf16x8 bh = __builtin_bit_cast(bf16x8, hw);
      const bf16x8 bl = __builtin_bit_cast(bf16x8, lw);
      a0 = __builtin_amdgcn_mfma_f32_32x32x16_bf16(Ah, bh, a0, 0, 0, 0);
      a1 = __builtin_amdgcn_mfma_f32_32x32x16_bf16(Ah, bl, a1, 0, 0, 0);
      a1 = __builtin_amdgcn_mfma_f32_32x32x16_bf16(Al, bh, a1, 0, 0, 0);
    }
  }

  // epilogue: C/D map (32x32): col = lane&31, row = (r&3)+8*(r>>2)+4*half
  const int b  = tau / STILES_PER_B;
  const int s0 = (tau % STILES_PER_B) * STW;
  float* ob = out + (size_t)b * PER_B + (size_t)s0 + m;
#pragma unroll
  for (int r = 0; r < 16; ++r) {
    const int row = (r & 3) + 8 * (r >> 2) + 4 * half;
    ob[(size_t)(c0 + row) * SPATIAL] = a0[r] + a1[r];
  }
}

extern "C" void kernel_launch(void* const* d_in, const int* in_sizes, int n_in,
                              void* d_out, int out_size, void* d_ws, size_t ws_size,
                              hipStream_t stream) {
  const float* x = (const float*)d_in[0];  // (32, 256, 56, 56) fp32
  const float* w = (const float*)d_in[1];  // (15,) fp32
  const int* ms = (const int*)d_in[2];     // scalar int (10)
  float* out = (float*)d_out;              // (32, 256, 56, 56) fp32

  // workspace: 2 x 96 KB fragment buffers = 192 KB total (< 256 KB proven)
  unsigned short* AhF = (unsigned short*)d_ws;       // 8*12*64*8*2B = 96 KB
  unsigned short* AlF = AhF + 8 * MAXCH * 64 * 8;    // 96 KB

  build_M_kernel<<<NCH, NCH, 0, stream>>>(w, ms, AhF, AlF);
  apply_M_kernel<<<NTILES, 512, 0, stream>>>(x, AhF, AlF, out);
}